// Round 10
// baseline (197.926 us; speedup 1.0000x reference)
//
#include <hip/hip_runtime.h>
#include <hip/hip_bf16.h>

// Problem constants
#define NN   4096      // nodes
#define FIN  1433      // input features
#define KPAD 1536      // padded K for GEMM1
#define NH   8         // heads
#define ND   64        // hidden per head
#define CD   512       // NH*ND

typedef float f32x4 __attribute__((ext_vector_type(4)));
typedef short s16x8 __attribute__((ext_vector_type(8)));   // 8 bf16

#define MFMA16(a, b, c) __builtin_amdgcn_mfma_f32_16x16x32_bf16((a), (b), (c), 0, 0, 0)

__device__ __forceinline__ void gload_lds16(const void* g, void* l) {
  __builtin_amdgcn_global_load_lds((const __attribute__((address_space(1))) void*)g,
                                   (__attribute__((address_space(3))) void*)l, 16, 0, 0);
}

__device__ __forceinline__ ushort f2bf(float x) {
  __hip_bfloat16 b = __float2bfloat16(x);
  ushort u;
  __builtin_memcpy(&u, &b, 2);
  return u;
}

// ---------------------------------------------------------------------------
// Kernel 1: f32 -> bf16 cast with K padding (1433 -> 1536, zero fill).
// ---------------------------------------------------------------------------
__global__ void castpad_kernel(const float* __restrict__ src, ushort* __restrict__ dst,
                               int rows, int kin, int kout) {
  int i = blockIdx.x * blockDim.x + threadIdx.x;   // one 8-elem group
  int kg = kout >> 3;
  int total = rows * kg;
  if (i >= total) return;
  int r  = i / kg;
  int k0 = (i - r * kg) << 3;
  s16x8 v;
#pragma unroll
  for (int j = 0; j < 8; ++j) {
    int k = k0 + j;
    float f = (k < kin) ? src[(size_t)r * kin + k] : 0.0f;
    v[j] = (short)f2bf(f);
  }
  *reinterpret_cast<s16x8*>(&dst[(size_t)r * kout + k0]) = v;
}

// ---------------------------------------------------------------------------
// Kernel 2: GEMM1  g = vertex @ W_vert^T   (NT, both K-contiguous)
// Round-9: was 512 blocks = 2/CU, latency-bound (no counters, inferred
// ~90 us from wall-total). Now 32x64 tiles -> 1024 blocks x 128 thr
// (2 waves, wave tile 32x32), BK=64 dbuf, 24 KB LDS -> 4 blocks/CU:
// 2x independent pipelines per CU to overlap stage-drain stalls.
// XCD row-band decode: XCD x owns 16 consecutive row-tiles, all cols
// (A-band 1.57 MB + B 1.5 MB fits 4 MB XCD-L2).
// ---------------------------------------------------------------------------
__global__ __launch_bounds__(128) void gemm1_kernel(const ushort* __restrict__ A,
                                                    const ushort* __restrict__ B,
                                                    ushort* __restrict__ G) {
  __shared__ ushort As[2][32][64];   // 4 KB per buf
  __shared__ ushort Bs[2][64][64];   // 8 KB per buf
  const int tid  = threadIdx.x;      // 0..127
  const int lane = tid & 63;
  const int w    = tid >> 6;         // wave 0..1

  const int b    = blockIdx.x;           // 0..1023
  const int x    = b & 7;                // XCD
  const int slot = b >> 3;               // 0..127
  const int by   = x * 16 + (slot >> 3); // row tile 0..127 (M=32 each)
  const int bx   = slot & 7;             // col tile 0..7  (N=64 each)
  const int row0 = by * 32;
  const int col0 = bx * 64;

  f32x4 acc[2][2] = {};   // wave tile 32x32: 2 M-frags x 2 N-frags

  // A: 32x64 bf16 = 256 chunks (2 wave-instr/wave); B: 64x64 = 512 chunks
  // (4 wave-instr/wave). Row = 8 chunks; fetch chunk cp^(r&7) (involution).
  auto stage = [&](int buf, int k0) {
#pragma unroll
    for (int j = 0; j < 2; ++j) {
      int ci = (w * 2 + j) * 64 + lane;   // 0..255
      int r  = ci >> 3;
      int cp = ci & 7;
      int gc = cp ^ (r & 7);
      gload_lds16(A + (size_t)(row0 + r) * KPAD + k0 + gc * 8,
                  &As[buf][0][0] + (size_t)(w * 2 + j) * 512);
    }
#pragma unroll
    for (int j = 0; j < 4; ++j) {
      int ci = (w * 4 + j) * 64 + lane;   // 0..511
      int r  = ci >> 3;
      int cp = ci & 7;
      int gc = cp ^ (r & 7);
      gload_lds16(B + (size_t)(col0 + r) * KPAD + k0 + gc * 8,
                  &Bs[buf][0][0] + (size_t)(w * 4 + j) * 512);
    }
  };

  stage(0, 0);
  __syncthreads();
  int cur = 0;

  for (int k0 = 0; k0 < KPAD; k0 += 64) {
    if (k0 + 64 < KPAD) stage(cur ^ 1, k0 + 64);   // prefetch next K-tile
#pragma unroll
    for (int kk = 0; kk < 2; ++kk) {               // 2 x K=32 sub-steps
      int kq = kk * 4 + (lane >> 4);               // chunk 0..7 within row
      s16x8 af[2], bfv[2];
#pragma unroll
      for (int f = 0; f < 2; ++f) {
        int ar = f * 16 + (lane & 15);             // A rows 0..31
        af[f]  = *reinterpret_cast<const s16x8*>(&As[cur][ar][(kq ^ (ar & 7)) * 8]);
        int br = w * 32 + f * 16 + (lane & 15);    // B cols (this wave's 32)
        bfv[f] = *reinterpret_cast<const s16x8*>(&Bs[cur][br][(kq ^ (br & 7)) * 8]);
      }
#pragma unroll
      for (int fi = 0; fi < 2; ++fi)
#pragma unroll
        for (int fj = 0; fj < 2; ++fj)
          acc[fi][fj] = MFMA16(af[fi], bfv[fj], acc[fi][fj]);
    }
    __syncthreads();
    cur ^= 1;
  }

  // epilogue: C/D layout col=lane&15, row=(lane>>4)*4+reg
#pragma unroll
  for (int fi = 0; fi < 2; ++fi)
#pragma unroll
    for (int fj = 0; fj < 2; ++fj)
#pragma unroll
      for (int r = 0; r < 4; ++r) {
        int gr   = row0 + fi * 16 + (lane >> 4) * 4 + r;
        int gcol = col0 + w * 32 + fj * 16 + (lane & 15);
        G[(size_t)gr * CD + gcol] = f2bf(acc[fi][fj][r]);
      }
}

// ---------------------------------------------------------------------------
// Kernel 3: fused Gram + head-mix + lrelu + head-sum.
// Round-9 counters: WRITE 107 MB, FETCH 55 MB, hbm 2.1 TB/s, MfmaUtil 4%
// -> latency-bound; output stream evicts G from XCD-L2 so stage loads are
// ~900cy HBM misses with only 2 blk/CU of cover. v5: NONTEMPORAL output
// stores with the (now) contiguous lane mapping — full 128B bursts that
// bypass L2 entirely -> G stays L2-resident, loads become ~200cy hits.
// ---------------------------------------------------------------------------
__global__ __launch_bounds__(256, 2) void gram_kernel(const ushort* __restrict__ G,
                                                      const float* __restrict__ Wattn,
                                                      float* __restrict__ out) {
  // ---- triangular tile decode with XCD swizzle ----
  const int nwg = (NN / 64) * (NN / 64 + 1) / 2;   // 2080
  const int cpx = nwg / 8;                          // 260
  int b = blockIdx.x;
  int t = (b % 8) * cpx + (b / 8);                  // bijective: 2080 % 8 == 0
  int bi = (int)((129.0f - sqrtf(16641.0f - 8.0f * (float)t)) * 0.5f);
  while ((129 * (bi + 1) - (bi + 1) * (bi + 1)) / 2 <= t) ++bi;
  while ((129 * bi - bi * bi) / 2 > t) --bi;
  const int bj = bi + (t - (129 * bi - bi * bi) / 2);
  const int ri0 = bi * 64, ci0 = bj * 64;

  __shared__ union LdsU {
    struct { ushort A[2][64][128]; ushort B[2][64][128]; } s;  // 4 x 16 KB
    struct { float t1[64][65]; float t2[64][65]; } wbuf;       // 33 KB
  } lds;
  __shared__ float sW[8][8];

  const int tid  = threadIdx.x;
  const int lane = tid & 63;
  const int w    = tid >> 6;
  const int wr   = w >> 1, wc = w & 1;

  if (tid < 64) sW[tid >> 3][tid & 7] = Wattn[tid];

  f32x4 acc[8][2][2] = {};   // [head][fi][fj] — fully static indexing

  // stage heads 2s,2s+1 into buf (16 KB per operand, 4 DMA/thread/operand)
  auto stage = [&](int buf, int s) {
#pragma unroll
    for (int j = 0; j < 4; ++j) {
      int ci = (w * 4 + j) * 64 + lane;   // 0..1023
      int r  = ci >> 4;
      int cp = ci & 15;
      int gc = cp ^ (r & 7);
      gload_lds16(G + (size_t)(ri0 + r) * CD + s * 128 + gc * 8,
                  &lds.s.A[buf][0][0] + (size_t)(w * 4 + j) * 512);
      gload_lds16(G + (size_t)(ci0 + r) * CD + s * 128 + gc * 8,
                  &lds.s.B[buf][0][0] + (size_t)(w * 4 + j) * 512);
    }
  };

  auto compute = [&](int buf, int s) {
#pragma unroll
    for (int hh = 0; hh < 2; ++hh) {
#pragma unroll
      for (int kk = 0; kk < 2; ++kk) {
        int kq = hh * 8 + kk * 4 + (lane >> 4);
        s16x8 af[2], bfv[2];
#pragma unroll
        for (int f = 0; f < 2; ++f) {
          int ar = wr * 32 + f * 16 + (lane & 15);
          af[f]  = *reinterpret_cast<const s16x8*>(
                     &lds.s.A[buf][ar][(kq ^ (ar & 7)) * 8]);
          int br = wc * 32 + f * 16 + (lane & 15);
          bfv[f] = *reinterpret_cast<const s16x8*>(
                     &lds.s.B[buf][br][(kq ^ (br & 7)) * 8]);
        }
        int h = s * 2 + hh;
#pragma unroll
        for (int fi = 0; fi < 2; ++fi)
#pragma unroll
          for (int fj = 0; fj < 2; ++fj)
            acc[h][fi][fj] = MFMA16(af[fi], bfv[fj], acc[h][fi][fj]);
      }
    }
  };

  stage(0, 0);
  __syncthreads();
  int cur = 0;
#pragma unroll
  for (int s = 0; s < 4; ++s) {
    if (s < 3) stage(cur ^ 1, s + 1);   // prefetch overlaps compute
    compute(cur, s);
    __syncthreads();                    // joins + drains prefetch DMA
    cur ^= 1;
  }

  // Epilogue: z_g = sum_h gram_h * W[g][h];  out = sum_g lrelu(z_g)
  float o[2][2][4] = {};
#pragma unroll
  for (int g = 0; g < 8; ++g) {
    float z[2][2][4] = {};
#pragma unroll
    for (int h = 0; h < 8; ++h) {
      float wgh = sW[g][h];
#pragma unroll
      for (int fi = 0; fi < 2; ++fi)
#pragma unroll
        for (int fj = 0; fj < 2; ++fj)
#pragma unroll
          for (int r = 0; r < 4; ++r)
            z[fi][fj][r] = fmaf(acc[h][fi][fj][r], wgh, z[fi][fj][r]);
    }
#pragma unroll
    for (int fi = 0; fi < 2; ++fi)
#pragma unroll
      for (int fj = 0; fj < 2; ++fj)
#pragma unroll
        for (int r = 0; r < 4; ++r) {
          float zz = z[fi][fj][r];
          o[fi][fj][r] += fmaxf(zz, 0.2f * zz);   // leaky relu, slope 0.2
        }
  }

  // ---- write phase: stage BOTH tiles into LDS, then store with the
  // contiguous lane mapping (16 lanes = 256B row = 2 full 128B lines per
  // instruction) via NONTEMPORAL stores (bypass L2, keep G resident).
  const bool mir = (bi != bj);
#pragma unroll
  for (int fi = 0; fi < 2; ++fi)
#pragma unroll
    for (int fj = 0; fj < 2; ++fj)
#pragma unroll
      for (int r = 0; r < 4; ++r) {
        int rr = wr * 32 + fi * 16 + (lane >> 4) * 4 + r;
        int cc = wc * 32 + fj * 16 + (lane & 15);
        float v = o[fi][fj][r];
        lds.wbuf.t1[rr][cc] = v;        // row-major (direct tile)
        lds.wbuf.t2[cc][rr] = v;        // transposed (mirror tile)
      }
  __syncthreads();
  const int rsub = tid >> 4;          // 0..15
  const int colf = (tid & 15) * 4;    // f32 column
#pragma unroll
  for (int it = 0; it < 4; ++it) {
    int row = it * 16 + rsub;
    f32x4 v1;
#pragma unroll
    for (int e = 0; e < 4; ++e) v1[e] = lds.wbuf.t1[row][colf + e];
    __builtin_nontemporal_store(
        v1, reinterpret_cast<f32x4*>(&out[(size_t)(ri0 + row) * NN + ci0 + colf]));
    if (mir) {
      f32x4 v2;
#pragma unroll
      for (int e = 0; e < 4; ++e) v2[e] = lds.wbuf.t2[row][colf + e];
      __builtin_nontemporal_store(
          v2, reinterpret_cast<f32x4*>(&out[(size_t)(ci0 + row) * NN + ri0 + colf]));
    }
  }
}

// ---------------------------------------------------------------------------
extern "C" void kernel_launch(void* const* d_in, const int* in_sizes, int n_in,
                              void* d_out, int out_size, void* d_ws, size_t ws_size,
                              hipStream_t stream) {
  const float* vertex = (const float*)d_in[0];   // [4096][1433] f32
  const float* Wvert  = (const float*)d_in[1];   // [512][1433]  f32
  const float* Wattn  = (const float*)d_in[2];   // [8][8]       f32
  float* out = (float*)d_out;                    // [4096][4096] f32

  char* ws = (char*)d_ws;
  ushort* Va = (ushort*)ws;                                           // [4096][1536] bf16
  ushort* Wb = (ushort*)(ws + (size_t)NN * KPAD * 2);                 // [512][1536]  bf16
  ushort* G  = (ushort*)(ws + (size_t)NN * KPAD * 2 + (size_t)CD * KPAD * 2); // [4096][512] bf16

  int tot1 = NN * (KPAD / 8);
  castpad_kernel<<<(tot1 + 255) / 256, 256, 0, stream>>>(vertex, Va, NN, FIN, KPAD);
  int tot2 = CD * (KPAD / 8);
  castpad_kernel<<<(tot2 + 255) / 256, 256, 0, stream>>>(Wvert, Wb, CD, FIN, KPAD);

  gemm1_kernel<<<1024, 128, 0, stream>>>(Va, Wb, G);

  int ntri = (NN / 64) * (NN / 64 + 1) / 2;   // 2080
  gram_kernel<<<ntri, 256, 0, stream>>>(G, Wattn, out);
}